// Round 1
// baseline (706.929 us; speedup 1.0000x reference)
//
#include <hip/hip_runtime.h>
#include <math.h>

#define N_TOK 16384
#define DDIM  384
#define KCODE 8192
#define EMA   0.99f
#define EPS_F 1e-5f
#define MARGIN 0.5f
#define NB 32            // KCODE / 256 code-blocks in coarse pass

typedef _Float16 f16x8 __attribute__((ext_vector_type(8)));
typedef float    f32x4 __attribute__((ext_vector_type(4)));

// ---- ws byte offsets (total 12,780,032 B <= proven 13,041,672 B) ----
// Region A [0, 12582912):
//   phase1 (argmin):   pd1/pi1/pd2 [0..6291456) + cbh f16 [6291456..12582912)
//   phase2 (rescore):  prd/pri [0..2097152)   (pd* dead after topmerge)
//   phase3 (scatter):  embed accum [0..12582912)
#define OFF_PD1    0UL        // [NB][N_TOK] f32 coarse best dist
#define OFF_PI1    2097152UL  // [NB][N_TOK] i32 coarse best idx
#define OFF_PD2    4194304UL  // [NB][N_TOK] f32 coarse 2nd dist
#define OFF_CBH    6291456UL  // [KCODE*DDIM] f16 pre-converted codebook
#define OFF_PRD    0UL        // [16][N_TOK] f32 rescore best dist (phase2)
#define OFF_PRI    1048576UL  // [16][N_TOK] i32 rescore best idx  (phase2)
#define OFF_EMBED  0UL        // phase3: [KCODE*DDIM] f32
// outside region A:
#define OFF_WSIDX  12582912UL // [N_TOK] i32
#define OFF_COUNTS 12648448UL // [KCODE] f32
#define OFF_SUMSQ  12681216UL // f32
#define OFF_NACC   12681220UL // f32 (+pad to 12681472)
#define OFF_CNORM  12681472UL // [KCODE] f32
#define OFF_FLIST  12714240UL // [N_TOK] i32 flagged tokens
#define OFF_FCNT   12779776UL // i32 + pad

// async global->LDS, 16B per lane; dest = wave-uniform base + lane*16
typedef __attribute__((address_space(1))) const unsigned int gas_uint;
typedef __attribute__((address_space(3))) unsigned int       las_uint;
__device__ __forceinline__ void gload_lds16(const void* g, void* l) {
    __builtin_amdgcn_global_load_lds((gas_uint*)g, (las_uint*)l, 16, 0, 0);
}

__global__ void cnorm_kernel(const float* __restrict__ cb, float* __restrict__ cnorm) {
    int wave = (blockIdx.x * blockDim.x + threadIdx.x) >> 6;
    int lane = threadIdx.x & 63;
    if (wave >= KCODE) return;
    const float* row = cb + (size_t)wave * DDIM;
    float s = 0.f;
    #pragma unroll
    for (int r = 0; r < 6; r++) { float v = row[lane + 64 * r]; s += v * v; }
    #pragma unroll
    for (int off = 32; off > 0; off >>= 1) s += __shfl_down(s, off, 64);
    if (lane == 0) cnorm[wave] = s;
}

// one-shot fp32 -> f16 conversion of z (into out_q scratch) and cb (into ws).
// flat: 8 elems / thread, float4x2 load, f16x8 store.
__global__ void convert_kernel(const float* __restrict__ z, const float* __restrict__ cb,
                               _Float16* __restrict__ zh, _Float16* __restrict__ cbh) {
    size_t e = ((size_t)blockIdx.x * blockDim.x + threadIdx.x) * 8;
    const size_t NZ = (size_t)N_TOK * DDIM;
    const float* s;
    _Float16* d;
    if (e < NZ) { s = z + e; d = zh + e; }
    else        { s = cb + (e - NZ); d = cbh + (e - NZ); }
    float4 v0 = *(const float4*)(s);
    float4 v1 = *(const float4*)(s + 4);
    f16x8 h;
    h[0]=(_Float16)v0.x; h[1]=(_Float16)v0.y; h[2]=(_Float16)v0.z; h[3]=(_Float16)v0.w;
    h[4]=(_Float16)v1.x; h[5]=(_Float16)v1.y; h[6]=(_Float16)v1.z; h[7]=(_Float16)v1.w;
    *(f16x8*)d = h;
}

// ---- coarse pass: f16 MFMA GEMM (z . c^T) with per-token top-2 over 256-code blocks ----
// block = 512 threads = 8 waves (wy in {0,1} token-half, wx in {0..3} code-quarter)
// tile 128 tokens x 256 codes, BK=32, 12 K-iters
// staging via global_load_lds width=16 from pre-converted f16 (zero staging VALU)
__launch_bounds__(512)
__global__ void argmin16_kernel(const _Float16* __restrict__ zh, const _Float16* __restrict__ cbh,
                                const float* __restrict__ cnorm,
                                float* __restrict__ pd1, int* __restrict__ pi1,
                                float* __restrict__ pd2) {
    __shared__ _Float16 As[128 * 32];   // 8 KB, rows 64B (b128-aligned frags)
    __shared__ _Float16 Bs[256 * 32];   // 16 KB
    __shared__ float xd1[128 * 4];
    __shared__ float xd2[128 * 4];
    __shared__ int   xi1[128 * 4];

    const int tid  = threadIdx.x;
    const int lane = tid & 63;
    const int wv   = tid >> 6;
    const int wy   = wv >> 2;
    const int wx   = wv & 3;
    const int m0   = blockIdx.x * 128;
    const int n0   = blockIdx.y * 256;
    const int l15  = lane & 15;
    const int l4   = lane >> 4;

    f32x4 acc[4][4];
    #pragma unroll
    for (int i = 0; i < 4; i++)
        #pragma unroll
        for (int j = 0; j < 4; j++) acc[i][j] = (f32x4){0.f, 0.f, 0.f, 0.f};

    // staging map: thread q stages 16B to LDS byte q*16 (row q>>2, col-quarter q&3)
    const int arow = tid >> 2, ac4 = tid & 3;
    const _Float16* a_src  = zh  + (size_t)(m0 + arow) * DDIM + ac4 * 8;
    const _Float16* b_src0 = cbh + (size_t)(n0 + arow) * DDIM + ac4 * 8;          // q = tid
    const _Float16* b_src1 = cbh + (size_t)(n0 + 128 + arow) * DDIM + ac4 * 8;    // q = tid+512
    _Float16* a_dst  = As + wv * 512;          // wave-uniform LDS base (bytes wv*1024)
    _Float16* b_dst0 = Bs + wv * 512;
    _Float16* b_dst1 = Bs + wv * 512 + 4096;   // +8192 bytes

    for (int kc = 0; kc < DDIM; kc += 32) {
        gload_lds16(a_src + kc,  a_dst);
        gload_lds16(b_src0 + kc, b_dst0);
        gload_lds16(b_src1 + kc, b_dst1);
        __syncthreads();   // compiler drains vmcnt(0) before s_barrier
        f16x8 af[4], bf[4];
        #pragma unroll
        for (int im = 0; im < 4; im++)
            af[im] = *(const f16x8*)(As + (wy * 64 + im * 16 + l15) * 32 + l4 * 8);
        #pragma unroll
        for (int in = 0; in < 4; in++)
            bf[in] = *(const f16x8*)(Bs + (wx * 64 + in * 16 + l15) * 32 + l4 * 8);
        #pragma unroll
        for (int im = 0; im < 4; im++)
            #pragma unroll
            for (int in = 0; in < 4; in++)
                acc[im][in] = __builtin_amdgcn_mfma_f32_16x16x32_f16(af[im], bf[in], acc[im][in], 0, 0, 0);
        __syncthreads();
    }

    // epilogue: dist = ||c||^2 - 2 z.c ; per-token top-2.
    // C/D layout: col(code)=lane&15, row(token)=(lane>>4)*4+reg
    float cn[4]; int cid[4];
    #pragma unroll
    for (int in = 0; in < 4; in++) {
        cid[in] = n0 + wx * 64 + in * 16 + l15;
        cn[in] = cnorm[cid[in]];
    }
    #pragma unroll
    for (int im = 0; im < 4; im++) {
        #pragma unroll
        for (int reg = 0; reg < 4; reg++) {
            float d1 = cn[0] - 2.f * acc[im][0][reg];
            int   i1 = cid[0];
            float d2 = 3.4e38f;
            #pragma unroll
            for (int in = 1; in < 4; in++) {
                float dd = cn[in] - 2.f * acc[im][in][reg];
                if (dd < d1) { d2 = d1; d1 = dd; i1 = cid[in]; }
                else d2 = fminf(d2, dd);
            }
            #pragma unroll
            for (int off = 1; off < 16; off <<= 1) {
                float od1 = __shfl_xor(d1, off, 16);
                int   oi1 = __shfl_xor(i1, off, 16);
                float od2 = __shfl_xor(d2, off, 16);
                if (od1 < d1 || (od1 == d1 && oi1 < i1)) { d2 = fminf(d1, od2); d1 = od1; i1 = oi1; }
                else d2 = fminf(d2, od1);
            }
            if (l15 == 0) {
                int tl = wy * 64 + im * 16 + l4 * 4 + reg;
                xd1[tl * 4 + wx] = d1; xi1[tl * 4 + wx] = i1; xd2[tl * 4 + wx] = d2;
            }
        }
    }
    __syncthreads();
    if (tid < 128) {
        float d1 = xd1[tid * 4], d2 = xd2[tid * 4];
        int   i1 = xi1[tid * 4];
        #pragma unroll
        for (int x = 1; x < 4; x++) {
            float od1 = xd1[tid * 4 + x], od2 = xd2[tid * 4 + x];
            int   oi1 = xi1[tid * 4 + x];
            if (od1 < d1 || (od1 == d1 && oi1 < i1)) { d2 = fminf(d1, od2); d1 = od1; i1 = oi1; }
            else d2 = fminf(d2, od1);
        }
        size_t o = (size_t)blockIdx.y * N_TOK + m0 + tid;
        pd1[o] = d1; pi1[o] = i1; pd2[o] = d2;
    }
}

// merge 32 coarse partials per token; flag near-ties (gap < MARGIN) for exact rescore
__global__ void topmerge_kernel(const float* __restrict__ pd1, const int* __restrict__ pi1,
                                const float* __restrict__ pd2,
                                int* __restrict__ ws_idx, float* __restrict__ out_idx,
                                int* __restrict__ fcnt, int* __restrict__ flist) {
    int t = blockIdx.x * blockDim.x + threadIdx.x;
    if (t >= N_TOK) return;
    float d1 = pd1[t], d2 = pd2[t];
    int   i1 = pi1[t];
    for (int nb = 1; nb < NB; nb++) {
        size_t o = (size_t)nb * N_TOK + t;
        float od1 = pd1[o], od2 = pd2[o];
        int   oi1 = pi1[o];
        if (od1 < d1 || (od1 == d1 && oi1 < i1)) { d2 = fminf(d1, od2); d1 = od1; i1 = oi1; }
        else d2 = fminf(d2, od1);
    }
    ws_idx[t] = i1;
    out_idx[t] = (float)i1;
    if (d2 - d1 < MARGIN) {
        int s = atomicAdd(fcnt, 1);
        flist[s] = t;
    }
}

// exact fp32 rescore of flagged tokens: 16 code-splits x groups of 8 tokens
__launch_bounds__(256)
__global__ void rescore_kernel(const float* __restrict__ z, const float* __restrict__ cb,
                               const float* __restrict__ cnorm,
                               const int* __restrict__ flist, const int* __restrict__ fcnt,
                               float* __restrict__ prd, int* __restrict__ pri) {
    __shared__ float zt[8 * 384];
    __shared__ float rd[8 * 4];
    __shared__ int   ri[8 * 4];
    const int tid = threadIdx.x;
    const int lane = tid & 63, wv = tid >> 6;
    const int s = blockIdx.x;
    const int count = fcnt[0];
    for (int g = blockIdx.y; g * 8 < count; g += 256) {
        #pragma unroll
        for (int r = 0; r < 3; r++) {
            int q = tid + r * 256;
            int j = q / 96, d4 = q % 96;
            int slot = g * 8 + j; if (slot >= count) slot = count - 1;
            int tok = flist[slot];
            *(float4*)(zt + j * 384 + d4 * 4) = *(const float4*)(z + (size_t)tok * DDIM + d4 * 4);
        }
        __syncthreads();
        float bd[8]; int bi[8];
        #pragma unroll
        for (int j = 0; j < 8; j++) { bd[j] = 3.4e38f; bi[j] = 0; }
        #pragma unroll
        for (int cc = 0; cc < 2; cc++) {
            int c = s * 512 + cc * 256 + tid;
            const float* cr = cb + (size_t)c * DDIM;
            float a[8];
            #pragma unroll
            for (int j = 0; j < 8; j++) a[j] = 0.f;
            for (int d4 = 0; d4 < 96; d4++) {
                float4 cv = *(const float4*)(cr + d4 * 4);
                #pragma unroll
                for (int j = 0; j < 8; j++) {
                    float4 zv = *(const float4*)(zt + j * 384 + d4 * 4);
                    a[j] = fmaf(zv.x, cv.x, a[j]);
                    a[j] = fmaf(zv.y, cv.y, a[j]);
                    a[j] = fmaf(zv.z, cv.z, a[j]);
                    a[j] = fmaf(zv.w, cv.w, a[j]);
                }
            }
            float cnv = cnorm[c];
            #pragma unroll
            for (int j = 0; j < 8; j++) {
                float dd = cnv - 2.f * a[j];
                if (dd < bd[j]) { bd[j] = dd; bi[j] = c; }
            }
        }
        #pragma unroll
        for (int j = 0; j < 8; j++) {
            float d = bd[j]; int i = bi[j];
            #pragma unroll
            for (int off = 32; off > 0; off >>= 1) {
                float od = __shfl_xor(d, off, 64);
                int   oi = __shfl_xor(i, off, 64);
                if (od < d || (od == d && oi < i)) { d = od; i = oi; }
            }
            if (lane == 0) { rd[j * 4 + wv] = d; ri[j * 4 + wv] = i; }
        }
        __syncthreads();
        if (tid < 8) {
            float d = rd[tid * 4]; int i = ri[tid * 4];
            #pragma unroll
            for (int x = 1; x < 4; x++) {
                float od = rd[tid * 4 + x]; int oi = ri[tid * 4 + x];
                if (od < d || (od == d && oi < i)) { d = od; i = oi; }
            }
            int slot = g * 8 + tid; if (slot >= count) slot = count - 1;
            int tok = flist[slot];
            prd[(size_t)s * N_TOK + tok] = d;
            pri[(size_t)s * N_TOK + tok] = i;
        }
        __syncthreads();
    }
}

__global__ void rsmerge_kernel(const float* __restrict__ prd, const int* __restrict__ pri,
                               const int* __restrict__ flist, const int* __restrict__ fcnt,
                               int* __restrict__ ws_idx, float* __restrict__ out_idx) {
    int slot = blockIdx.x * blockDim.x + threadIdx.x;
    if (slot >= fcnt[0]) return;
    int tok = flist[slot];
    float d = prd[tok]; int i = pri[tok];
    for (int s = 1; s < 16; s++) {
        float od = prd[(size_t)s * N_TOK + tok];
        int   oi = pri[(size_t)s * N_TOK + tok];
        if (od < d || (od == d && oi < i)) { d = od; i = oi; }
    }
    ws_idx[tok] = i;
    out_idx[tok] = (float)i;
}

__global__ void gather_scatter_kernel(const float* __restrict__ z, const float* __restrict__ cb,
                                      const int* __restrict__ ws_idx,
                                      float* __restrict__ out_q, float* __restrict__ embed_ws,
                                      float* __restrict__ counts, float* __restrict__ sumsq) {
    int t = (blockIdx.x * blockDim.x + threadIdx.x) >> 6;
    int lane = threadIdx.x & 63;
    if (t >= N_TOK) return;
    int k = ws_idx[t];
    const float* zr = z + (size_t)t * DDIM;
    const float* cr = cb + (size_t)k * DDIM;
    float* qr = out_q + (size_t)t * DDIM;
    float* er = embed_ws + (size_t)k * DDIM;
    float s = 0.f;
    #pragma unroll
    for (int r = 0; r < 6; r++) {
        int d = lane + 64 * r;
        float zv = zr[d];
        float qv = cr[d];
        qr[d] = qv;
        float df = zv - qv;
        s += df * df;
        atomicAdd(er + d, zv);
    }
    #pragma unroll
    for (int off = 32; off > 0; off >>= 1) s += __shfl_down(s, off, 64);
    if (lane == 0) {
        atomicAdd(sumsq, s);
        atomicAdd(counts + k, 1.0f);
    }
}

__global__ void cluster_kernel(const float* __restrict__ ema_cs, const float* __restrict__ counts,
                               float* __restrict__ out_ncs, float* __restrict__ n_acc,
                               const float* __restrict__ sumsq, float* __restrict__ out_loss) {
    int i = blockIdx.x * blockDim.x + threadIdx.x;
    float v = 0.f;
    if (i < KCODE) {
        v = EMA * ema_cs[i] + (1.f - EMA) * counts[i];
        out_ncs[i] = v;
    }
    __shared__ float sm[4];
    int lane = threadIdx.x & 63, w = threadIdx.x >> 6;
    #pragma unroll
    for (int off = 32; off > 0; off >>= 1) v += __shfl_down(v, off, 64);
    if (lane == 0) sm[w] = v;
    __syncthreads();
    if (threadIdx.x == 0) {
        atomicAdd(n_acc, sm[0] + sm[1] + sm[2] + sm[3]);
        if (blockIdx.x == 0) {
            out_loss[0] = 1.25f * sumsq[0] / (float)(N_TOK * DDIM);
        }
    }
}

__global__ void codebook_kernel(const float* __restrict__ ema_es, const float* __restrict__ embed_ws,
                                const float* __restrict__ ncs, const float* __restrict__ n_acc,
                                float* __restrict__ out_es, float* __restrict__ out_cb) {
    int i = blockIdx.x * blockDim.x + threadIdx.x;
    if (i >= KCODE * DDIM) return;
    float es = EMA * ema_es[i] + (1.f - EMA) * embed_ws[i];
    out_es[i] = es;
    int k = i / DDIM;
    float n = n_acc[0];
    float smooth = (ncs[k] + EPS_F) / (n + (float)KCODE * EPS_F) * n;
    out_cb[i] = es / smooth;
}

extern "C" void kernel_launch(void* const* d_in, const int* in_sizes, int n_in,
                              void* d_out, int out_size, void* d_ws, size_t ws_size,
                              hipStream_t stream) {
    const float* z       = (const float*)d_in[0];
    const float* cb      = (const float*)d_in[1];
    const float* ema_cs  = (const float*)d_in[2];
    const float* ema_es  = (const float*)d_in[3];

    float* out      = (float*)d_out;
    float* out_q    = out;
    float* out_idx  = out + 6291456;
    float* out_loss = out + 6307840;
    float* out_ncs  = out + 6307841;
    float* out_es   = out + 6316033;
    float* out_cb   = out + 9461761;

    char* w = (char*)d_ws;
    float* pd1    = (float*)(w + OFF_PD1);
    int*   pi1    = (int*)  (w + OFF_PI1);
    float* pd2    = (float*)(w + OFF_PD2);
    _Float16* cbh = (_Float16*)(w + OFF_CBH);
    float* prd    = (float*)(w + OFF_PRD);
    int*   pri    = (int*)  (w + OFF_PRI);
    float* cnorm  = (float*)(w + OFF_CNORM);
    int*   flist  = (int*)  (w + OFF_FLIST);
    int*   fcnt   = (int*)  (w + OFF_FCNT);
    float* embed  = (float*)(w + OFF_EMBED);
    int*   ws_idx = (int*)  (w + OFF_WSIDX);
    float* counts = (float*)(w + OFF_COUNTS);
    float* sumsq  = (float*)(w + OFF_SUMSQ);
    float* n_acc  = (float*)(w + OFF_NACC);

    // zh scratch lives in out_q's first 12.58 MB (out_q fully rewritten later)
    _Float16* zh = (_Float16*)out;

    hipMemsetAsync(w + OFF_FCNT, 0, 256, stream);
    hipMemsetAsync(w + OFF_COUNTS, 0, 32768 + 256, stream);  // counts + sumsq + n_acc

    cnorm_kernel<<<KCODE * 64 / 256, 256, 0, stream>>>(cb, cnorm);

    // (N_TOK + KCODE) * DDIM / 8 elems-per-thread / 256 threads = 4608 blocks
    convert_kernel<<<4608, 256, 0, stream>>>(z, cb, zh, cbh);

    dim3 grid_am(N_TOK / 128, KCODE / 256, 1);
    argmin16_kernel<<<grid_am, 512, 0, stream>>>(zh, cbh, cnorm, pd1, pi1, pd2);

    topmerge_kernel<<<N_TOK / 256, 256, 0, stream>>>(pd1, pi1, pd2, ws_idx, out_idx, fcnt, flist);

    dim3 grid_rs(16, 256, 1);
    rescore_kernel<<<grid_rs, 256, 0, stream>>>(z, cb, cnorm, flist, fcnt, prd, pri);
    rsmerge_kernel<<<N_TOK / 256, 256, 0, stream>>>(prd, pri, flist, fcnt, ws_idx, out_idx);

    // partials are dead now; reuse region A as the embed-sum accumulator
    hipMemsetAsync(w + OFF_EMBED, 0, (size_t)KCODE * DDIM * sizeof(float), stream);

    gather_scatter_kernel<<<N_TOK * 64 / 256, 256, 0, stream>>>(z, cb, ws_idx, out_q, embed, counts, sumsq);
    cluster_kernel<<<(KCODE + 255) / 256, 256, 0, stream>>>(ema_cs, counts, out_ncs, n_acc, sumsq, out_loss);
    codebook_kernel<<<(KCODE * DDIM) / 256, 256, 0, stream>>>(ema_es, embed, out_ncs, n_acc, out_es, out_cb);
}